// Round 4
// baseline (402.469 us; speedup 1.0000x reference)
//
#include <hip/hip_runtime.h>
#include <math.h>

#define NN 6000
#define NE 12000
#define MAXD 64
// HC=128, H=4, D=32

typedef _Float16 f16;
typedef _Float16 f16x8 __attribute__((ext_vector_type(8)));
typedef unsigned short u16x8 __attribute__((ext_vector_type(8)));
typedef float f32x4 __attribute__((ext_vector_type(4)));

__device__ __forceinline__ float gelu_f(float x) {
    return 0.5f * x * (1.0f + erff(x * 0.70710678118654752f));
}

// ---------------- precompute: Bmat[i][k][768] = [M0|M1|M2|M3|M4|root] ----------------
__global__ __launch_bounds__(256) void k_pre_bmat(
    const float* __restrict__ nn_w, const float* __restrict__ nn_b,
    const float* __restrict__ nn_root,
    const float* __restrict__ eew, const float* __restrict__ eeb,
    float* __restrict__ Bmat)
{
    __shared__ float enc[5][128];
    int tid = threadIdx.x;
    for (int l = tid; l < 640; l += 256) {
        int j = l >> 7, k = l & 127;
        enc[j][k] = (j < 4) ? eew[j * 128 + k] : eeb[k];
    }
    __syncthreads();
    int gid = blockIdx.x * 256 + tid;       // 8 * 16384 total
    int i = gid >> 14;
    int col = gid & 16383;                  // k_in*128 + o
    int k_in = col >> 7, o = col & 127;
    const float* w = nn_w + (size_t)i * (128 * 16384) + col;
    float a0 = 0.f, a1 = 0.f, a2 = 0.f, a3 = 0.f, a4 = 0.f;
    #pragma unroll 8
    for (int k = 0; k < 128; ++k) {
        float wv = w[(size_t)k * 16384];
        a0 += enc[0][k] * wv; a1 += enc[1][k] * wv; a2 += enc[2][k] * wv;
        a3 += enc[3][k] * wv; a4 += enc[4][k] * wv;
    }
    a4 += nn_b[i * 16384 + col];
    float* brow = Bmat + (size_t)(i * 128 + k_in) * 768;
    brow[0 * 128 + o] = a0; brow[1 * 128 + o] = a1; brow[2 * 128 + o] = a2;
    brow[3 * 128 + o] = a3; brow[4 * 128 + o] = a4;
    brow[640 + o] = nn_root[i * 16384 + col];
}

// B2T[i][o][j*128+k] = BMAT[i][k][j*128+o], f16 hi/lo split. grid (8,6)
__global__ __launch_bounds__(256) void k_split_b2(
    const float* __restrict__ Bmat, f16* __restrict__ bh, f16* __restrict__ bl)
{
    __shared__ float tile[128][129];
    int i = blockIdx.x, j = blockIdx.y, tid = threadIdx.x;
    const float* s = Bmat + (size_t)i * 98304;
    for (int l = tid; l < 16384; l += 256) {
        int k = l >> 7, o = l & 127;
        tile[k][o] = s[(size_t)k * 768 + j * 128 + o];
    }
    __syncthreads();
    size_t dbase = (size_t)i * 98304 + j * 128;
    for (int l = tid; l < 16384; l += 256) {
        int o = l >> 7, k = l & 127;
        float v = tile[k][o];
        f16 h = (f16)v;
        f16 lo = (f16)(v - (float)h);
        bh[dbase + (size_t)o * 768 + k] = h;
        bl[dbase + (size_t)o * 768 + k] = lo;
    }
}

// WT[i][half*128+o][k] = w[i][k][o], f16 hi/lo. grid (2,2): (layer, l/r)
__global__ __launch_bounds__(256) void k_split_gat(
    const float* __restrict__ wl, const float* __restrict__ wr,
    f16* __restrict__ bh, f16* __restrict__ bl)
{
    __shared__ float tile[128][129];
    int i = blockIdx.x, half = blockIdx.y, tid = threadIdx.x;
    const float* s = (half ? wr : wl) + (size_t)i * 16384;
    for (int l = tid; l < 16384; l += 256) {
        int k = l >> 7, o = l & 127;
        tile[k][o] = s[k * 128 + o];
    }
    __syncthreads();
    size_t dbase = (size_t)i * 32768 + (size_t)half * 16384;
    for (int l = tid; l < 16384; l += 256) {
        int o = l >> 7, k = l & 127;
        float v = tile[k][o];
        f16 h = (f16)v;
        f16 lo = (f16)(v - (float)h);
        bh[dbase + o * 128 + k] = h;
        bl[dbase + o * 128 + k] = lo;
    }
}

// EW[i][j][o] (1280) then biasLR[2][256] (512)
__global__ void k_pre_ew(const float* __restrict__ gat_e_w,
    const float* __restrict__ eew, const float* __restrict__ eeb,
    const float* __restrict__ lb, const float* __restrict__ rb,
    float* __restrict__ EW, float* __restrict__ biasLR)
{
    int idx = blockIdx.x * 256 + threadIdx.x;
    if (idx < 1280) {
        int i = idx / 640; int r = idx % 640; int j = r >> 7; int o = r & 127;
        float s = 0.f;
        for (int k = 0; k < 128; ++k) {
            float e = (j < 4) ? eew[j * 128 + k] : eeb[k];
            s += e * gat_e_w[i * 16384 + k * 128 + o];
        }
        EW[idx] = s;
    } else if (idx < 1792) {
        int j = idx - 1280; int i = j >> 8; int c = j & 255;
        biasLR[j] = (c < 128) ? lb[i * 128 + c] : rb[i * 128 + c - 128];
    }
}

__global__ void k_node_enc(const float* __restrict__ x,
    const float* __restrict__ w, float* __restrict__ h0,
    f16* __restrict__ hf, int* __restrict__ cnt)
{
    int idx = blockIdx.x * 256 + threadIdx.x;   // N*128
    int n = idx >> 7, c = idx & 127;
    float s = 0.f;
    #pragma unroll
    for (int f = 0; f < 6; ++f) s += x[n * 6 + f] * w[f * 128 + c];
    h0[idx] = s;
    hf[idx] = (f16)s;
    if (c == 0) cnt[n] = 0;
}

// ---------------- CSR build ----------------
__global__ void k_csr_count(const int* __restrict__ ei, int* __restrict__ cnt)
{
    int e = blockIdx.x * 256 + threadIdx.x;
    if (e < NE) atomicAdd(&cnt[ei[NE + e]], 1);
}

__global__ __launch_bounds__(1024) void k_csr_scan(
    const int* __restrict__ cnt, int* __restrict__ offs, int* __restrict__ cursor)
{
    __shared__ int carry;
    __shared__ int wsum[16];
    int tid = threadIdx.x, lane = tid & 63, w = tid >> 6;
    if (tid == 0) { carry = 0; offs[0] = 0; }
    __syncthreads();
    for (int base = 0; base < NN; base += 1024) {
        int i = base + tid;
        int v = (i < NN) ? cnt[i] : 0;
        int x = v;
        for (int o = 1; o < 64; o <<= 1) {
            int y = __shfl_up(x, o, 64);
            if (lane >= o) x += y;
        }
        if (lane == 63) wsum[w] = x;
        __syncthreads();
        if (tid == 0) {
            int a = 0;
            for (int w2 = 0; w2 < 16; ++w2) { int t = wsum[w2]; wsum[w2] = a; a += t; }
        }
        __syncthreads();
        int incl = x + wsum[w] + carry;
        if (i < NN) { offs[i + 1] = incl; cursor[i] = incl - v; }
        __syncthreads();
        if (tid == 1023) carry = incl;
        __syncthreads();
    }
}

__global__ void k_csr_scatter(const int* __restrict__ ei,
    int* __restrict__ cursor, int* __restrict__ eidx)
{
    int e = blockIdx.x * 256 + threadIdx.x;
    if (e < NE) {
        int d = ei[NE + e];
        int pos = atomicAdd(&cursor[d], 1);
        eidx[pos] = e;
    }
}

// ---------------- generic MFMA matmul (GAT): C[M,P] = A_f16 @ B^T + bias, 2-pass ----------------
// A:[M,128] f16; B stored [P][128] f16 hi/lo. 64x64 tile, 256 thr.
__global__ __launch_bounds__(256) void k_mm16(
    const f16* __restrict__ A, const f16* __restrict__ Bh, const f16* __restrict__ Bl,
    const float* __restrict__ bias, float* __restrict__ C, int M, int P)
{
    __shared__ __align__(16) unsigned short smem[24576];   // 48KB: sA|sBh|sBl
    unsigned short* sA  = smem;
    unsigned short* sBh = smem + 8192;
    unsigned short* sBl = smem + 16384;
    const int tid = threadIdx.x;
    const int r0 = blockIdx.x * 64, n0 = blockIdx.y * 64;
    #pragma unroll
    for (int i = 0; i < 4; ++i) {
        int g = tid + i * 256; int row = g >> 4, u = g & 15;
        int dst = row * 128 + ((u ^ (row & 7)) << 3);
        int r = r0 + row;
        if (r < M) *(u16x8*)&sA[dst] = *(const u16x8*)((const unsigned short*)A + (size_t)r * 128 + u * 8);
        else { u16x8 z; for (int j = 0; j < 8; ++j) z[j] = 0; *(u16x8*)&sA[dst] = z; }
        size_t sb = (size_t)(n0 + row) * 128 + u * 8;
        *(u16x8*)&sBh[dst] = *(const u16x8*)((const unsigned short*)Bh + sb);
        *(u16x8*)&sBl[dst] = *(const u16x8*)((const unsigned short*)Bl + sb);
    }
    __syncthreads();
    const int lane = tid & 63, wid = tid >> 6;
    const int wm = wid & 1, wn = wid >> 1;
    const int l15 = lane & 15, lg = lane >> 4;
    f32x4 acc[2][2] = {};
    #pragma unroll
    for (int kk = 0; kk < 4; ++kk) {
        f16x8 a[2], bh_[2], bl_[2];
        #pragma unroll
        for (int fm = 0; fm < 2; ++fm) {
            int row = wm * 32 + fm * 16 + l15;
            int off = row * 128 + ((((kk << 2) + lg) ^ (row & 7)) << 3);
            a[fm] = *(const f16x8*)&sA[off];
        }
        #pragma unroll
        for (int fn = 0; fn < 2; ++fn) {
            int row = wn * 32 + fn * 16 + l15;
            int off = row * 128 + ((((kk << 2) + lg) ^ (row & 7)) << 3);
            bh_[fn] = *(const f16x8*)&sBh[off];
            bl_[fn] = *(const f16x8*)&sBl[off];
        }
        #pragma unroll
        for (int fm = 0; fm < 2; ++fm)
        #pragma unroll
        for (int fn = 0; fn < 2; ++fn) {
            acc[fm][fn] = __builtin_amdgcn_mfma_f32_16x16x32_f16(a[fm], bh_[fn], acc[fm][fn], 0, 0, 0);
            acc[fm][fn] = __builtin_amdgcn_mfma_f32_16x16x32_f16(a[fm], bl_[fn], acc[fm][fn], 0, 0, 0);
        }
    }
    #pragma unroll
    for (int fn = 0; fn < 2; ++fn) {
        int col = n0 + wn * 32 + fn * 16 + l15;
        float bv = bias ? bias[col] : 0.f;
        #pragma unroll
        for (int fm = 0; fm < 2; ++fm) {
            int rbase = r0 + wm * 32 + fm * 16 + lg * 4;
            #pragma unroll
            for (int j = 0; j < 4; ++j) {
                int r = rbase + j;
                if (r < M) C[(size_t)r * P + col] = acc[fm][fn][j] + bv;
            }
        }
    }
}

// ---------------- fused GATv2 layer (per-dst CSR) ----------------
__global__ __launch_bounds__(256) void k_gat_fused(
    const float* __restrict__ XLXR, const int* __restrict__ ei,
    const float* __restrict__ eattr, const int* __restrict__ offs,
    const int* __restrict__ eidx, const float* __restrict__ EW,
    const float* __restrict__ att, float* __restrict__ h0,
    const float* __restrict__ bias, const float* __restrict__ g,
    const float* __restrict__ b,
    f16* __restrict__ hf, int hstride)
{
    __shared__ float slog[4][MAXD][4];
    __shared__ float sms[4][4][2];
    int rowl = threadIdx.x >> 6, lane = threadIdx.x & 63;
    int r = blockIdx.x * 4 + rowl;
    int o0 = offs[r], deg = offs[r + 1] - o0;
    if (deg > MAXD) deg = MAXD;
    float xr0 = XLXR[r * 256 + 128 + lane];
    float xr1 = XLXR[r * 256 + 192 + lane];
    float e0 = EW[lane], e1 = EW[128 + lane], e2 = EW[256 + lane], e3 = EW[384 + lane], e4 = EW[512 + lane];
    float f0 = EW[64 + lane], f1 = EW[192 + lane], f2 = EW[320 + lane], f3 = EW[448 + lane], f4 = EW[576 + lane];
    float at0 = att[lane], at1 = att[64 + lane];
    for (int k = 0; k < deg; ++k) {
        int e = eidx[o0 + k]; int s = ei[e];
        float a0 = eattr[e * 4 + 0], a1 = eattr[e * 4 + 1];
        float a2 = eattr[e * 4 + 2], a3 = eattr[e * 4 + 3];
        float g0 = XLXR[s * 256 + lane]      + xr0 + (a0 * e0 + a1 * e1 + a2 * e2 + a3 * e3 + e4);
        float g1 = XLXR[s * 256 + 64 + lane] + xr1 + (a0 * f0 + a1 * f1 + a2 * f2 + a3 * f3 + f4);
        g0 = (g0 > 0.f) ? g0 : 0.1f * g0;
        g1 = (g1 > 0.f) ? g1 : 0.1f * g1;
        float p0 = g0 * at0, p1 = g1 * at1;
        for (int o = 16; o; o >>= 1) { p0 += __shfl_xor(p0, o, 32); p1 += __shfl_xor(p1, o, 32); }
        if ((lane & 31) == 0) {
            int hh2 = lane >> 5;
            slog[rowl][k][hh2] = p0;
            slog[rowl][k][2 + hh2] = p1;
        }
    }
    if (lane < 4) {
        float mh = -1e30f;
        for (int k = 0; k < deg; ++k) mh = fmaxf(mh, slog[rowl][k][lane]);
        float sh = 0.f;
        for (int k = 0; k < deg; ++k) sh += expf(slog[rowl][k][lane] - mh);
        sms[rowl][lane][0] = mh; sms[rowl][lane][1] = sh;
    }
    int hd = lane >> 5;
    float m0 = sms[rowl][hd][0], s0 = sms[rowl][hd][1];
    float m1 = sms[rowl][2 + hd][0], s1 = sms[rowl][2 + hd][1];
    float acc0 = 0.f, acc1 = 0.f;
    for (int k = 0; k < deg; ++k) {
        int e = eidx[o0 + k]; int s = ei[e];
        float al0 = expf(slog[rowl][k][hd] - m0) / (s0 + 1e-16f);
        float al1 = expf(slog[rowl][k][2 + hd] - m1) / (s1 + 1e-16f);
        acc0 += al0 * XLXR[s * 256 + lane];
        acc1 += al1 * XLXR[s * 256 + 64 + lane];
    }
    float v0 = h0[r * 128 + lane]      + acc0 + bias[lane];
    float v1 = h0[r * 128 + 64 + lane] + acc1 + bias[64 + lane];
    float sum = v0 + v1;
    for (int o = 32; o; o >>= 1) sum += __shfl_xor(sum, o, 64);
    float mean = sum * 0.0078125f;
    float d0 = v0 - mean, d1 = v1 - mean;
    float var = d0 * d0 + d1 * d1;
    for (int o = 32; o; o >>= 1) var += __shfl_xor(var, o, 64);
    float inv = rsqrtf(var * 0.0078125f + 1e-5f);
    float y0 = gelu_f(d0 * inv * g[lane] + b[lane]);
    float y1 = gelu_f(d1 * inv * g[64 + lane] + b[64 + lane]);
    h0[r * 128 + lane] = y0; h0[r * 128 + 64 + lane] = y1;
    hf[(size_t)r * hstride + lane] = (f16)y0;
    hf[(size_t)r * hstride + 64 + lane] = (f16)y1;
}

// ---------------- S gather: SA[d][j*128+c] = sum_{e->d} a_j(e) * T[src][c]; T = SA[.][640:768]
__global__ __launch_bounds__(256) void k_sgather(
    const int* __restrict__ ei, const float* __restrict__ eattr,
    const int* __restrict__ offs, const int* __restrict__ eidx,
    f16* __restrict__ SA)
{
    int rowl = threadIdx.x >> 6, lane = threadIdx.x & 63;
    int d = blockIdx.x * 4 + rowl;
    int o0 = offs[d], deg = offs[d + 1] - o0;
    float acc[5][2] = {};
    for (int k = 0; k < deg; ++k) {
        int e = eidx[o0 + k]; int s = ei[e];
        float a0 = eattr[e * 4 + 0], a1 = eattr[e * 4 + 1];
        float a2 = eattr[e * 4 + 2], a3 = eattr[e * 4 + 3];
        float t0 = (float)SA[(size_t)s * 768 + 640 + lane];
        float t1 = (float)SA[(size_t)s * 768 + 704 + lane];
        acc[0][0] += a0 * t0; acc[1][0] += a1 * t0; acc[2][0] += a2 * t0;
        acc[3][0] += a3 * t0; acc[4][0] += t0;
        acc[0][1] += a0 * t1; acc[1][1] += a1 * t1; acc[2][1] += a2 * t1;
        acc[3][1] += a3 * t1; acc[4][1] += t1;
    }
    f16* dst = SA + (size_t)d * 768;
    #pragma unroll
    for (int j = 0; j < 5; ++j) {
        dst[j * 128 + lane] = (f16)acc[j][0];
        dst[j * 128 + 64 + lane] = (f16)acc[j][1];
    }
}

// ---------------- conv matmul + fused epilogue ----------------
// out32 = SA[6000,768]f16 @ B2T^T (+nn_bias). 32 rows x 128 cols per block, grid 188.
// epilogue: Hnew = (h0+Hprev)+out (or out for init); T' = gelu(ln(h0+Hnew)) -> SA[.,640:768]
// final: y = gelu(ln(Hnew)); out = y@out_w + out_b
__global__ __launch_bounds__(256) void k_convmm(
    const f16* __restrict__ SA, const f16* __restrict__ B2h, const f16* __restrict__ B2l,
    const float* __restrict__ bias,
    const float* __restrict__ h0, const float* __restrict__ Hprev,
    float* __restrict__ H,
    const float* __restrict__ lng, const float* __restrict__ lnb,
    int final_mode,
    const float* __restrict__ outw, const float* __restrict__ outb,
    float* __restrict__ outp)
{
    __shared__ __align__(16) unsigned short smem[36864];   // 72KB: sA 8K | sBh 32K | sBl 32K
    unsigned short* sA  = smem;          // 32x128 f16
    unsigned short* sBh = smem + 4096;   // 128x128 f16
    unsigned short* sBl = smem + 20480;
    float* sOut = (float*)smem;          // reuse after compute: 32x132 f32
    const int tid = threadIdx.x;
    const int r0 = blockIdx.x * 32;
    const int lane = tid & 63, w = tid >> 6, l15 = lane & 15, lg = lane >> 4;
    f32x4 acc[2][2] = {};
    for (int kc = 0; kc < 6; ++kc) {
        #pragma unroll
        for (int i = 0; i < 2; ++i) {
            int g = tid + i * 256; int row = g >> 4, u = g & 15;
            int dst = row * 128 + ((u ^ (row & 7)) << 3);
            int r = r0 + row;
            if (r < NN) *(u16x8*)&sA[dst] = *(const u16x8*)((const unsigned short*)SA + (size_t)r * 768 + kc * 128 + u * 8);
            else { u16x8 z; for (int j = 0; j < 8; ++j) z[j] = 0; *(u16x8*)&sA[dst] = z; }
        }
        #pragma unroll
        for (int i = 0; i < 8; ++i) {
            int g = tid + i * 256; int row = g >> 4, u = g & 15;
            int dst = row * 128 + ((u ^ (row & 7)) << 3);
            size_t src = (size_t)row * 768 + kc * 128 + u * 8;
            *(u16x8*)&sBh[dst] = *(const u16x8*)((const unsigned short*)B2h + src);
            *(u16x8*)&sBl[dst] = *(const u16x8*)((const unsigned short*)B2l + src);
        }
        __syncthreads();
        #pragma unroll
        for (int kk = 0; kk < 4; ++kk) {
            f16x8 a[2], bh_[2], bl_[2];
            #pragma unroll
            for (int fm = 0; fm < 2; ++fm) {
                int row = fm * 16 + l15;
                int off = row * 128 + ((((kk << 2) + lg) ^ (row & 7)) << 3);
                a[fm] = *(const f16x8*)&sA[off];
            }
            #pragma unroll
            for (int fn = 0; fn < 2; ++fn) {
                int o = w * 32 + fn * 16 + l15;
                int off = o * 128 + ((((kk << 2) + lg) ^ (o & 7)) << 3);
                bh_[fn] = *(const f16x8*)&sBh[off];
                bl_[fn] = *(const f16x8*)&sBl[off];
            }
            #pragma unroll
            for (int fm = 0; fm < 2; ++fm)
            #pragma unroll
            for (int fn = 0; fn < 2; ++fn) {
                acc[fm][fn] = __builtin_amdgcn_mfma_f32_16x16x32_f16(a[fm], bh_[fn], acc[fm][fn], 0, 0, 0);
                acc[fm][fn] = __builtin_amdgcn_mfma_f32_16x16x32_f16(a[fm], bl_[fn], acc[fm][fn], 0, 0, 0);
            }
        }
        __syncthreads();
    }
    // acc -> sOut
    #pragma unroll
    for (int fm = 0; fm < 2; ++fm)
    #pragma unroll
    for (int fn = 0; fn < 2; ++fn) {
        int col = w * 32 + fn * 16 + l15;
        #pragma unroll
        for (int j = 0; j < 4; ++j) {
            int row = fm * 16 + lg * 4 + j;
            sOut[row * 132 + col] = acc[fm][fn][j];
        }
    }
    __syncthreads();
    // per-row epilogue: wave w handles rows 4t+w
    for (int t = 0; t < 8; ++t) {
        int row = t * 4 + w;
        int r = r0 + row;
        if (r >= NN) continue;
        float v0 = sOut[row * 132 + lane] + bias[lane];
        float v1 = sOut[row * 132 + 64 + lane] + bias[64 + lane];
        float hz0 = h0[r * 128 + lane], hz1 = h0[r * 128 + 64 + lane];
        if (Hprev) {
            v0 += hz0 + Hprev[r * 128 + lane];
            v1 += hz1 + Hprev[r * 128 + 64 + lane];
        }
        float u0, u1;
        if (!final_mode) {
            H[r * 128 + lane] = v0; H[r * 128 + 64 + lane] = v1;
            u0 = hz0 + v0; u1 = hz1 + v1;
        } else {
            u0 = v0; u1 = v1;
        }
        float sum = u0 + u1;
        for (int o = 32; o; o >>= 1) sum += __shfl_xor(sum, o, 64);
        float mean = sum * 0.0078125f;
        float d0 = u0 - mean, d1 = u1 - mean;
        float var = d0 * d0 + d1 * d1;
        for (int o = 32; o; o >>= 1) var += __shfl_xor(var, o, 64);
        float inv = rsqrtf(var * 0.0078125f + 1e-5f);
        float y0 = gelu_f(d0 * inv * lng[lane] + lnb[lane]);
        float y1 = gelu_f(d1 * inv * lng[64 + lane] + lnb[64 + lane]);
        if (!final_mode) {
            f16* dst = (f16*)((unsigned short*)0) ;
            // write T' into SA cols 640:768
            ((f16*)SA)[(size_t)r * 768 + 640 + lane] = (f16)y0;
            ((f16*)SA)[(size_t)r * 768 + 704 + lane] = (f16)y1;
            (void)dst;
        } else {
            float p0 = y0 * outw[lane * 2 + 0] + y1 * outw[(64 + lane) * 2 + 0];
            float p1 = y0 * outw[lane * 2 + 1] + y1 * outw[(64 + lane) * 2 + 1];
            for (int o = 32; o; o >>= 1) { p0 += __shfl_xor(p0, o, 64); p1 += __shfl_xor(p1, o, 64); }
            if (lane == 0) {
                outp[r * 2 + 0] = p0 + outb[0];
                outp[r * 2 + 1] = p1 + outb[1];
            }
        }
    }
}

extern "C" void kernel_launch(void* const* d_in, const int* in_sizes, int n_in,
                              void* d_out, int out_size, void* d_ws, size_t ws_size,
                              hipStream_t stream)
{
    const float* x        = (const float*)d_in[0];
    const int*   ei       = (const int*)d_in[1];
    const float* eattr    = (const float*)d_in[2];
    const float* node_w   = (const float*)d_in[4];
    const float* eew      = (const float*)d_in[5];
    const float* eeb      = (const float*)d_in[6];
    const float* gat_l_w  = (const float*)d_in[7];
    const float* gat_l_b  = (const float*)d_in[8];
    const float* gat_r_w  = (const float*)d_in[9];
    const float* gat_r_b  = (const float*)d_in[10];
    const float* gat_e_w  = (const float*)d_in[11];
    const float* gat_att  = (const float*)d_in[12];
    const float* gat_bias = (const float*)d_in[13];
    const float* gat_ln_g = (const float*)d_in[14];
    const float* gat_ln_b = (const float*)d_in[15];
    const float* nn_w     = (const float*)d_in[16];
    const float* nn_b     = (const float*)d_in[17];
    const float* nn_root  = (const float*)d_in[18];
    const float* nn_bias  = (const float*)d_in[19];
    const float* dec_g    = (const float*)d_in[20];
    const float* dec_b    = (const float*)d_in[21];
    const float* out_w    = (const float*)d_in[22];
    const float* out_b    = (const float*)d_in[23];
    float* out = (float*)d_out;

    float* ws    = (float*)d_ws;
    float* BMAT  = ws;                        // 786432
    float* EW    = BMAT + 786432;             // 1280
    float* BLR   = EW + 1280;                 // 512
    float* H0    = BLR + 512;                 // 768000
    float* H     = H0 + 768000;               // 768000
    float* XLXR  = H + 768000;                // 1536000
    int*   CNT   = (int*)(XLXR + 1536000);    // 6000
    int*   OFFS  = CNT + 6000;                // 6001
    int*   CURS  = OFFS + 6001;               // 6000
    int*   EIDX  = CURS + 6000;               // 12000 (+1 pad)
    f16*   B2h   = (f16*)(EIDX + 12001);      // 8*128*768 = 786432
    f16*   B2l   = B2h + 786432;
    f16*   WTh   = B2l + 786432;              // 2*256*128 = 65536
    f16*   WTl   = WTh + 65536;
    f16*   H0F   = WTl + 65536;               // 768000
    f16*   SA    = H0F + 768000;              // 6000*768 = 4608000

    dim3 b256(256);
    hipLaunchKernelGGL(k_pre_bmat, dim3(512), b256, 0, stream, nn_w, nn_b, nn_root, eew, eeb, BMAT);
    hipLaunchKernelGGL(k_split_b2, dim3(8, 6), b256, 0, stream, BMAT, B2h, B2l);
    hipLaunchKernelGGL(k_split_gat, dim3(2, 2), b256, 0, stream, gat_l_w, gat_r_w, WTh, WTl);
    hipLaunchKernelGGL(k_pre_ew, dim3(7), b256, 0, stream, gat_e_w, eew, eeb, gat_l_b, gat_r_b, EW, BLR);
    hipLaunchKernelGGL(k_node_enc, dim3(3000), b256, 0, stream, x, node_w, H0, H0F, CNT);
    hipLaunchKernelGGL(k_csr_count, dim3(47), b256, 0, stream, ei, CNT);
    hipLaunchKernelGGL(k_csr_scan, dim3(1), dim3(1024), 0, stream, CNT, OFFS, CURS);
    hipLaunchKernelGGL(k_csr_scatter, dim3(47), b256, 0, stream, ei, CURS, EIDX);

    for (int i = 0; i < 2; ++i) {
        hipLaunchKernelGGL(k_mm16, dim3(94, 4), b256, 0, stream,
                           H0F, WTh + i * 32768, WTl + i * 32768,
                           BLR + i * 256, XLXR, NN, 256);
        if (i == 0)
            hipLaunchKernelGGL(k_gat_fused, dim3(1500), b256, 0, stream,
                               XLXR, ei, eattr, OFFS, EIDX, EW, gat_att,
                               H0, gat_bias, gat_ln_g, gat_ln_b, H0F, 128);
        else
            hipLaunchKernelGGL(k_gat_fused, dim3(1500), b256, 0, stream,
                               XLXR, ei, eattr, OFFS, EIDX, EW + 640, gat_att + 128,
                               H0, gat_bias + 128, gat_ln_g + 128, gat_ln_b + 128,
                               SA + 640, 768);
    }

    // initial conv (layer-0 weights), input T=h0 (SA cols 640:768)
    hipLaunchKernelGGL(k_sgather, dim3(1500), b256, 0, stream, ei, eattr, OFFS, EIDX, SA);
    hipLaunchKernelGGL(k_convmm, dim3(188), b256, 0, stream,
                       SA, B2h, B2l, nn_bias, H0, (const float*)nullptr, H,
                       dec_g, dec_b, 0, (const float*)nullptr, (const float*)nullptr, (float*)nullptr);

    for (int i = 0; i < 8; ++i) {
        int fin = (i == 7);
        hipLaunchKernelGGL(k_sgather, dim3(1500), b256, 0, stream, ei, eattr, OFFS, EIDX, SA);
        hipLaunchKernelGGL(k_convmm, dim3(188), b256, 0, stream,
                           SA, B2h + (size_t)i * 98304, B2l + (size_t)i * 98304,
                           nn_bias + i * 128, H0, H, H,
                           fin ? dec_g : dec_g + (i + 1) * 128,
                           fin ? dec_b : dec_b + (i + 1) * 128,
                           fin, out_w, out_b, out);
    }
}

// Round 5
// 394.061 us; speedup vs baseline: 1.0213x; 1.0213x over previous
//
#include <hip/hip_runtime.h>
#include <math.h>

#define NN 6000
#define NE 12000
#define DCAP 32
// HC=128, H=4, D=32

typedef _Float16 f16;
typedef _Float16 f16x8 __attribute__((ext_vector_type(8)));
typedef unsigned short u16x8 __attribute__((ext_vector_type(8)));
typedef float f32x4 __attribute__((ext_vector_type(4)));

__device__ __forceinline__ float gelu_f(float x) {
    return 0.5f * x * (1.0f + erff(x * 0.70710678118654752f));
}

// ---------------- precompute: Bmat[i][k][768] = [M0|M1|M2|M3|M4|root] ----------------
__global__ __launch_bounds__(256) void k_pre_bmat(
    const float* __restrict__ nn_w, const float* __restrict__ nn_b,
    const float* __restrict__ nn_root,
    const float* __restrict__ eew, const float* __restrict__ eeb,
    float* __restrict__ Bmat)
{
    __shared__ float enc[5][128];
    int tid = threadIdx.x;
    for (int l = tid; l < 640; l += 256) {
        int j = l >> 7, k = l & 127;
        enc[j][k] = (j < 4) ? eew[j * 128 + k] : eeb[k];
    }
    __syncthreads();
    int gid = blockIdx.x * 256 + tid;       // 8 * 16384 total
    int i = gid >> 14;
    int col = gid & 16383;                  // k_in*128 + o
    int k_in = col >> 7, o = col & 127;
    const float* w = nn_w + (size_t)i * (128 * 16384) + col;
    float a0 = 0.f, a1 = 0.f, a2 = 0.f, a3 = 0.f, a4 = 0.f;
    #pragma unroll 8
    for (int k = 0; k < 128; ++k) {
        float wv = w[(size_t)k * 16384];
        a0 += enc[0][k] * wv; a1 += enc[1][k] * wv; a2 += enc[2][k] * wv;
        a3 += enc[3][k] * wv; a4 += enc[4][k] * wv;
    }
    a4 += nn_b[i * 16384 + col];
    float* brow = Bmat + (size_t)(i * 128 + k_in) * 768;
    brow[0 * 128 + o] = a0; brow[1 * 128 + o] = a1; brow[2 * 128 + o] = a2;
    brow[3 * 128 + o] = a3; brow[4 * 128 + o] = a4;
    brow[640 + o] = nn_root[i * 16384 + col];
}

// B2T[i][o][j*128+k] = BMAT[i][k][j*128+o], f16 hi/lo split. grid (8,6)
__global__ __launch_bounds__(256) void k_split_b2(
    const float* __restrict__ Bmat, f16* __restrict__ bh, f16* __restrict__ bl)
{
    __shared__ float tile[128][129];
    int i = blockIdx.x, j = blockIdx.y, tid = threadIdx.x;
    const float* s = Bmat + (size_t)i * 98304;
    for (int l = tid; l < 16384; l += 256) {
        int k = l >> 7, o = l & 127;
        tile[k][o] = s[(size_t)k * 768 + j * 128 + o];
    }
    __syncthreads();
    size_t dbase = (size_t)i * 98304 + j * 128;
    for (int l = tid; l < 16384; l += 256) {
        int o = l >> 7, k = l & 127;
        float v = tile[k][o];
        f16 h = (f16)v;
        f16 lo = (f16)(v - (float)h);
        bh[dbase + (size_t)o * 768 + k] = h;
        bl[dbase + (size_t)o * 768 + k] = lo;
    }
}

// WT[i][half*128+o][k] = w[i][k][o], f16 hi/lo. grid (2,2): (layer, l/r)
__global__ __launch_bounds__(256) void k_split_gat(
    const float* __restrict__ wl, const float* __restrict__ wr,
    f16* __restrict__ bh, f16* __restrict__ bl)
{
    __shared__ float tile[128][129];
    int i = blockIdx.x, half = blockIdx.y, tid = threadIdx.x;
    const float* s = (half ? wr : wl) + (size_t)i * 16384;
    for (int l = tid; l < 16384; l += 256) {
        int k = l >> 7, o = l & 127;
        tile[k][o] = s[k * 128 + o];
    }
    __syncthreads();
    size_t dbase = (size_t)i * 32768 + (size_t)half * 16384;
    for (int l = tid; l < 16384; l += 256) {
        int o = l >> 7, k = l & 127;
        float v = tile[k][o];
        f16 h = (f16)v;
        f16 lo = (f16)(v - (float)h);
        bh[dbase + o * 128 + k] = h;
        bl[dbase + o * 128 + k] = lo;
    }
}

// EW[i][j][o] (1280) then biasLR[2][256] (512)
__global__ void k_pre_ew(const float* __restrict__ gat_e_w,
    const float* __restrict__ eew, const float* __restrict__ eeb,
    const float* __restrict__ lb, const float* __restrict__ rb,
    float* __restrict__ EW, float* __restrict__ biasLR)
{
    int idx = blockIdx.x * 256 + threadIdx.x;
    if (idx < 1280) {
        int i = idx / 640; int r = idx % 640; int j = r >> 7; int o = r & 127;
        float s = 0.f;
        for (int k = 0; k < 128; ++k) {
            float e = (j < 4) ? eew[j * 128 + k] : eeb[k];
            s += e * gat_e_w[i * 16384 + k * 128 + o];
        }
        EW[idx] = s;
    } else if (idx < 1792) {
        int j = idx - 1280; int i = j >> 8; int c = j & 255;
        biasLR[j] = (c < 128) ? lb[i * 128 + c] : rb[i * 128 + c - 128];
    }
}

__global__ void k_node_enc(const float* __restrict__ x,
    const float* __restrict__ w, float* __restrict__ h0,
    f16* __restrict__ hf, int* __restrict__ cnt)
{
    int idx = blockIdx.x * 256 + threadIdx.x;   // N*128
    int n = idx >> 7, c = idx & 127;
    float s = 0.f;
    #pragma unroll
    for (int f = 0; f < 6; ++f) s += x[n * 6 + f] * w[f * 128 + c];
    h0[idx] = s;
    hf[idx] = (f16)s;
    if (c == 0) cnt[n] = 0;
}

// bucket CSR: EB[d][k] = edge ids with dst d (cap DCAP)
__global__ void k_bucket(const int* __restrict__ ei,
    int* __restrict__ cnt, int* __restrict__ eb)
{
    int e = blockIdx.x * 256 + threadIdx.x;
    if (e < NE) {
        int d = ei[NE + e];
        int pos = atomicAdd(&cnt[d], 1);
        if (pos < DCAP) eb[d * DCAP + pos] = e;
    }
}

// ---------------- generic MFMA matmul (GAT): C[M,P] = A_f16 @ B^T + bias, 2-pass ----------------
__global__ __launch_bounds__(256) void k_mm16(
    const f16* __restrict__ A, const f16* __restrict__ Bh, const f16* __restrict__ Bl,
    const float* __restrict__ bias, float* __restrict__ C, int M, int P)
{
    __shared__ __align__(16) unsigned short smem[24576];   // 48KB: sA|sBh|sBl
    unsigned short* sA  = smem;
    unsigned short* sBh = smem + 8192;
    unsigned short* sBl = smem + 16384;
    const int tid = threadIdx.x;
    const int r0 = blockIdx.x * 64, n0 = blockIdx.y * 64;
    #pragma unroll
    for (int i = 0; i < 4; ++i) {
        int g = tid + i * 256; int row = g >> 4, u = g & 15;
        int dst = row * 128 + ((u ^ (row & 7)) << 3);
        int r = r0 + row;
        if (r < M) *(u16x8*)&sA[dst] = *(const u16x8*)((const unsigned short*)A + (size_t)r * 128 + u * 8);
        else { u16x8 z; for (int j = 0; j < 8; ++j) z[j] = 0; *(u16x8*)&sA[dst] = z; }
        size_t sb = (size_t)(n0 + row) * 128 + u * 8;
        *(u16x8*)&sBh[dst] = *(const u16x8*)((const unsigned short*)Bh + sb);
        *(u16x8*)&sBl[dst] = *(const u16x8*)((const unsigned short*)Bl + sb);
    }
    __syncthreads();
    const int lane = tid & 63, wid = tid >> 6;
    const int wm = wid & 1, wn = wid >> 1;
    const int l15 = lane & 15, lg = lane >> 4;
    f32x4 acc[2][2] = {};
    #pragma unroll
    for (int kk = 0; kk < 4; ++kk) {
        f16x8 a[2], bh_[2], bl_[2];
        #pragma unroll
        for (int fm = 0; fm < 2; ++fm) {
            int row = wm * 32 + fm * 16 + l15;
            int off = row * 128 + ((((kk << 2) + lg) ^ (row & 7)) << 3);
            a[fm] = *(const f16x8*)&sA[off];
        }
        #pragma unroll
        for (int fn = 0; fn < 2; ++fn) {
            int row = wn * 32 + fn * 16 + l15;
            int off = row * 128 + ((((kk << 2) + lg) ^ (row & 7)) << 3);
            bh_[fn] = *(const f16x8*)&sBh[off];
            bl_[fn] = *(const f16x8*)&sBl[off];
        }
        #pragma unroll
        for (int fm = 0; fm < 2; ++fm)
        #pragma unroll
        for (int fn = 0; fn < 2; ++fn) {
            acc[fm][fn] = __builtin_amdgcn_mfma_f32_16x16x32_f16(a[fm], bh_[fn], acc[fm][fn], 0, 0, 0);
            acc[fm][fn] = __builtin_amdgcn_mfma_f32_16x16x32_f16(a[fm], bl_[fn], acc[fm][fn], 0, 0, 0);
        }
    }
    #pragma unroll
    for (int fn = 0; fn < 2; ++fn) {
        int col = n0 + wn * 32 + fn * 16 + l15;
        float bv = bias ? bias[col] : 0.f;
        #pragma unroll
        for (int fm = 0; fm < 2; ++fm) {
            int rbase = r0 + wm * 32 + fm * 16 + lg * 4;
            #pragma unroll
            for (int j = 0; j < 4; ++j) {
                int r = rbase + j;
                if (r < M) C[(size_t)r * P + col] = acc[fm][fn][j] + bv;
            }
        }
    }
}

// ---------------- fused GATv2 layer (per-dst bucket) ----------------
__global__ __launch_bounds__(256) void k_gat_fused(
    const float* __restrict__ XLXR, const int* __restrict__ ei,
    const float* __restrict__ eattr, const int* __restrict__ cnt,
    const int* __restrict__ eb, const float* __restrict__ EW,
    const float* __restrict__ att, float* __restrict__ h0,
    const float* __restrict__ bias, const float* __restrict__ g,
    const float* __restrict__ b,
    f16* __restrict__ hf)
{
    __shared__ float slog[4][DCAP][4];
    __shared__ float sms[4][4][2];
    int rowl = threadIdx.x >> 6, lane = threadIdx.x & 63;
    int r = blockIdx.x * 4 + rowl;
    int deg = cnt[r]; if (deg > DCAP) deg = DCAP;
    float xr0 = XLXR[r * 256 + 128 + lane];
    float xr1 = XLXR[r * 256 + 192 + lane];
    float e0 = EW[lane], e1 = EW[128 + lane], e2 = EW[256 + lane], e3 = EW[384 + lane], e4 = EW[512 + lane];
    float f0 = EW[64 + lane], f1 = EW[192 + lane], f2 = EW[320 + lane], f3 = EW[448 + lane], f4 = EW[576 + lane];
    float at0 = att[lane], at1 = att[64 + lane];
    for (int k = 0; k < deg; ++k) {
        int e = eb[r * DCAP + k]; int s = ei[e];
        float a0 = eattr[e * 4 + 0], a1 = eattr[e * 4 + 1];
        float a2 = eattr[e * 4 + 2], a3 = eattr[e * 4 + 3];
        float g0 = XLXR[s * 256 + lane]      + xr0 + (a0 * e0 + a1 * e1 + a2 * e2 + a3 * e3 + e4);
        float g1 = XLXR[s * 256 + 64 + lane] + xr1 + (a0 * f0 + a1 * f1 + a2 * f2 + a3 * f3 + f4);
        g0 = (g0 > 0.f) ? g0 : 0.1f * g0;
        g1 = (g1 > 0.f) ? g1 : 0.1f * g1;
        float p0 = g0 * at0, p1 = g1 * at1;
        for (int o = 16; o; o >>= 1) { p0 += __shfl_xor(p0, o, 32); p1 += __shfl_xor(p1, o, 32); }
        if ((lane & 31) == 0) {
            int hh2 = lane >> 5;
            slog[rowl][k][hh2] = p0;
            slog[rowl][k][2 + hh2] = p1;
        }
    }
    if (lane < 4) {
        float mh = -1e30f;
        for (int k = 0; k < deg; ++k) mh = fmaxf(mh, slog[rowl][k][lane]);
        float sh = 0.f;
        for (int k = 0; k < deg; ++k) sh += expf(slog[rowl][k][lane] - mh);
        sms[rowl][lane][0] = mh; sms[rowl][lane][1] = sh;
    }
    int hd = lane >> 5;
    float m0 = sms[rowl][hd][0], s0 = sms[rowl][hd][1];
    float m1 = sms[rowl][2 + hd][0], s1 = sms[rowl][2 + hd][1];
    float acc0 = 0.f, acc1 = 0.f;
    for (int k = 0; k < deg; ++k) {
        int e = eb[r * DCAP + k]; int s = ei[e];
        float al0 = expf(slog[rowl][k][hd] - m0) / (s0 + 1e-16f);
        float al1 = expf(slog[rowl][k][2 + hd] - m1) / (s1 + 1e-16f);
        acc0 += al0 * XLXR[s * 256 + lane];
        acc1 += al1 * XLXR[s * 256 + 64 + lane];
    }
    float v0 = h0[r * 128 + lane]      + acc0 + bias[lane];
    float v1 = h0[r * 128 + 64 + lane] + acc1 + bias[64 + lane];
    float sum = v0 + v1;
    for (int o = 32; o; o >>= 1) sum += __shfl_xor(sum, o, 64);
    float mean = sum * 0.0078125f;
    float d0 = v0 - mean, d1 = v1 - mean;
    float var = d0 * d0 + d1 * d1;
    for (int o = 32; o; o >>= 1) var += __shfl_xor(var, o, 64);
    float inv = rsqrtf(var * 0.0078125f + 1e-5f);
    float y0 = gelu_f(d0 * inv * g[lane] + b[lane]);
    float y1 = gelu_f(d1 * inv * g[64 + lane] + b[64 + lane]);
    h0[r * 128 + lane] = y0; h0[r * 128 + 64 + lane] = y1;
    hf[r * 128 + lane] = (f16)y0;
    hf[r * 128 + 64 + lane] = (f16)y1;
}

// ---------------- fused NNConv: gather S into LDS A + matmul + epilogue ----------------
// block = 32 dst rows; A-tile [32][768] f16 (XOR-swizzled units) built from TF[src] gathers.
// out = A @ B^T (+nn_bias); epilogue: H, T' = gelu(ln(...)) -> TF; final: projection.
__global__ __launch_bounds__(256) void k_convmm(
    const f16* __restrict__ TF, const int* __restrict__ ei,
    const float* __restrict__ eattr, const int* __restrict__ cnt,
    const int* __restrict__ eb,
    const f16* __restrict__ B2h, const f16* __restrict__ B2l,
    const float* __restrict__ bias,
    const float* __restrict__ h0, const float* __restrict__ Hprev,
    float* __restrict__ H, f16* __restrict__ TFout,
    const float* __restrict__ lng, const float* __restrict__ lnb,
    int final_mode,
    const float* __restrict__ outw, const float* __restrict__ outb,
    float* __restrict__ outp)
{
    __shared__ __align__(16) unsigned short sA[24576];    // 32x768 f16, 48KB
    __shared__ __align__(16) unsigned short sBh[16384];   // 128x128 f16, 32KB
    __shared__ __align__(16) unsigned short sBl[16384];   // 32KB
    float* sOut = (float*)sBh;                            // alias after MFMA
    const int tid = threadIdx.x;
    const int r0 = blockIdx.x * 32;
    const int lane = tid & 63, w = tid >> 6;
    const int l15 = lane & 15, lg = lane >> 4;

    // ---- gather phase: each wave builds 8 rows of A ----
    for (int t = 0; t < 8; ++t) {
        int row = w * 8 + t;
        int r = r0 + row;
        float acc[5][2] = {};
        int deg = 0;
        if (r < NN) { deg = cnt[r]; if (deg > DCAP) deg = DCAP; }
        for (int k = 0; k < deg; ++k) {
            int e = eb[r * DCAP + k]; int s = ei[e];
            float a0 = eattr[e * 4 + 0], a1 = eattr[e * 4 + 1];
            float a2 = eattr[e * 4 + 2], a3 = eattr[e * 4 + 3];
            unsigned int tt = *(const unsigned int*)&TF[(size_t)s * 128 + lane * 2];
            float t0 = (float)__builtin_bit_cast(f16, (unsigned short)(tt & 0xffff));
            float t1 = (float)__builtin_bit_cast(f16, (unsigned short)(tt >> 16));
            acc[0][0] += a0 * t0; acc[1][0] += a1 * t0; acc[2][0] += a2 * t0;
            acc[3][0] += a3 * t0; acc[4][0] += t0;
            acc[0][1] += a0 * t1; acc[1][1] += a1 * t1; acc[2][1] += a2 * t1;
            acc[3][1] += a3 * t1; acc[4][1] += t1;
        }
        // write S cols {2*lane, 2*lane+1} for j=0..4, plus root cols (unit 80+)
        int rw = row & 7;
        #pragma unroll
        for (int j = 0; j < 5; ++j) {
            int u = j * 16 + (lane >> 2);
            int us = (u & ~7) | ((u & 7) ^ rw);
            unsigned short p0 = __builtin_bit_cast(unsigned short, (f16)acc[j][0]);
            unsigned short p1 = __builtin_bit_cast(unsigned short, (f16)acc[j][1]);
            *(unsigned int*)&sA[row * 768 + us * 8 + ((2 * lane) & 7)] =
                (unsigned int)p0 | ((unsigned int)p1 << 16);
        }
        unsigned int rt = 0;
        if (r < NN) rt = *(const unsigned int*)&TF[(size_t)r * 128 + lane * 2];
        int u = 80 + (lane >> 2);
        int us = (u & ~7) | ((u & 7) ^ rw);
        *(unsigned int*)&sA[row * 768 + us * 8 + ((2 * lane) & 7)] = rt;
    }
    __syncthreads();

    // ---- matmul phase ----
    f32x4 acc[2][2] = {};
    for (int kc = 0; kc < 6; ++kc) {
        #pragma unroll
        for (int i2 = 0; i2 < 8; ++i2) {
            int g = tid + i2 * 256; int brow = g >> 4, u = g & 15;
            int dst = brow * 128 + ((u ^ (brow & 7)) << 3);
            size_t src = (size_t)brow * 768 + kc * 128 + u * 8;
            *(u16x8*)&sBh[dst] = *(const u16x8*)((const unsigned short*)B2h + src);
            *(u16x8*)&sBl[dst] = *(const u16x8*)((const unsigned short*)B2l + src);
        }
        __syncthreads();
        #pragma unroll
        for (int kk = 0; kk < 4; ++kk) {
            f16x8 a[2], bh_[2], bl_[2];
            #pragma unroll
            for (int fm = 0; fm < 2; ++fm) {
                int row = fm * 16 + l15;
                int ug = kc * 16 + kk * 4 + lg;
                int ugs = (ug & ~7) | ((ug & 7) ^ (row & 7));
                a[fm] = *(const f16x8*)&sA[row * 768 + ugs * 8];
            }
            #pragma unroll
            for (int fn = 0; fn < 2; ++fn) {
                int brow = w * 32 + fn * 16 + l15;
                int ub = kk * 4 + lg;
                int off = brow * 128 + ((ub ^ (brow & 7)) << 3);
                bh_[fn] = *(const f16x8*)&sBh[off];
                bl_[fn] = *(const f16x8*)&sBl[off];
            }
            #pragma unroll
            for (int fm = 0; fm < 2; ++fm)
            #pragma unroll
            for (int fn = 0; fn < 2; ++fn) {
                acc[fm][fn] = __builtin_amdgcn_mfma_f32_16x16x32_f16(a[fm], bh_[fn], acc[fm][fn], 0, 0, 0);
                acc[fm][fn] = __builtin_amdgcn_mfma_f32_16x16x32_f16(a[fm], bl_[fn], acc[fm][fn], 0, 0, 0);
            }
        }
        __syncthreads();
    }
    // acc -> sOut (aliases sBh; sync above guarantees B reads done)
    #pragma unroll
    for (int fm = 0; fm < 2; ++fm)
    #pragma unroll
    for (int fn = 0; fn < 2; ++fn) {
        int col = w * 32 + fn * 16 + l15;
        #pragma unroll
        for (int j = 0; j < 4; ++j) {
            int row = fm * 16 + lg * 4 + j;
            sOut[row * 132 + col] = acc[fm][fn][j];
        }
    }
    __syncthreads();
    // per-row epilogue
    for (int t = 0; t < 8; ++t) {
        int row = t * 4 + w;
        int r = r0 + row;
        if (r >= NN) continue;
        float v0 = sOut[row * 132 + lane] + bias[lane];
        float v1 = sOut[row * 132 + 64 + lane] + bias[64 + lane];
        float hz0 = h0[r * 128 + lane], hz1 = h0[r * 128 + 64 + lane];
        if (Hprev) {
            v0 += hz0 + Hprev[r * 128 + lane];
            v1 += hz1 + Hprev[r * 128 + 64 + lane];
        }
        float u0, u1;
        if (!final_mode) {
            H[r * 128 + lane] = v0; H[r * 128 + 64 + lane] = v1;
            u0 = hz0 + v0; u1 = hz1 + v1;
        } else {
            u0 = v0; u1 = v1;
        }
        float sum = u0 + u1;
        for (int o = 32; o; o >>= 1) sum += __shfl_xor(sum, o, 64);
        float mean = sum * 0.0078125f;
        float d0 = u0 - mean, d1 = u1 - mean;
        float var = d0 * d0 + d1 * d1;
        for (int o = 32; o; o >>= 1) var += __shfl_xor(var, o, 64);
        float inv = rsqrtf(var * 0.0078125f + 1e-5f);
        float y0 = gelu_f(d0 * inv * lng[lane] + lnb[lane]);
        float y1 = gelu_f(d1 * inv * lng[64 + lane] + lnb[64 + lane]);
        if (!final_mode) {
            TFout[r * 128 + lane] = (f16)y0;
            TFout[r * 128 + 64 + lane] = (f16)y1;
        } else {
            float p0 = y0 * outw[lane * 2 + 0] + y1 * outw[(64 + lane) * 2 + 0];
            float p1 = y0 * outw[lane * 2 + 1] + y1 * outw[(64 + lane) * 2 + 1];
            for (int o = 32; o; o >>= 1) { p0 += __shfl_xor(p0, o, 64); p1 += __shfl_xor(p1, o, 64); }
            if (lane == 0) {
                outp[r * 2 + 0] = p0 + outb[0];
                outp[r * 2 + 1] = p1 + outb[1];
            }
        }
    }
}

extern "C" void kernel_launch(void* const* d_in, const int* in_sizes, int n_in,
                              void* d_out, int out_size, void* d_ws, size_t ws_size,
                              hipStream_t stream)
{
    const float* x        = (const float*)d_in[0];
    const int*   ei       = (const int*)d_in[1];
    const float* eattr    = (const float*)d_in[2];
    const float* node_w   = (const float*)d_in[4];
    const float* eew      = (const float*)d_in[5];
    const float* eeb      = (const float*)d_in[6];
    const float* gat_l_w  = (const float*)d_in[7];
    const float* gat_l_b  = (const float*)d_in[8];
    const float* gat_r_w  = (const float*)d_in[9];
    const float* gat_r_b  = (const float*)d_in[10];
    const float* gat_e_w  = (const float*)d_in[11];
    const float* gat_att  = (const float*)d_in[12];
    const float* gat_bias = (const float*)d_in[13];
    const float* gat_ln_g = (const float*)d_in[14];
    const float* gat_ln_b = (const float*)d_in[15];
    const float* nn_w     = (const float*)d_in[16];
    const float* nn_b     = (const float*)d_in[17];
    const float* nn_root  = (const float*)d_in[18];
    const float* nn_bias  = (const float*)d_in[19];
    const float* dec_g    = (const float*)d_in[20];
    const float* dec_b    = (const float*)d_in[21];
    const float* out_w    = (const float*)d_in[22];
    const float* out_b    = (const float*)d_in[23];
    float* out = (float*)d_out;

    float* ws    = (float*)d_ws;
    float* BMAT  = ws;                        // 786432
    float* EW    = BMAT + 786432;             // 1280
    float* BLR   = EW + 1280;                 // 512
    float* H0    = BLR + 512;                 // 768000
    float* H     = H0 + 768000;               // 768000
    float* XLXR  = H + 768000;                // 1536000
    int*   CNT   = (int*)(XLXR + 1536000);    // 6000
    int*   EB    = CNT + 6000;                // 6000*32 = 192000
    f16*   B2h   = (f16*)(EB + 192000);       // 8*128*768 = 786432
    f16*   B2l   = B2h + 786432;
    f16*   WTh   = B2l + 786432;              // 2*256*128 = 65536
    f16*   WTl   = WTh + 65536;
    f16*   H0F   = WTl + 65536;               // 768000
    f16*   TF    = H0F + 768000;              // 768000

    dim3 b256(256);
    hipLaunchKernelGGL(k_pre_bmat, dim3(512), b256, 0, stream, nn_w, nn_b, nn_root, eew, eeb, BMAT);
    hipLaunchKernelGGL(k_split_b2, dim3(8, 6), b256, 0, stream, BMAT, B2h, B2l);
    hipLaunchKernelGGL(k_split_gat, dim3(2, 2), b256, 0, stream, gat_l_w, gat_r_w, WTh, WTl);
    hipLaunchKernelGGL(k_pre_ew, dim3(7), b256, 0, stream, gat_e_w, eew, eeb, gat_l_b, gat_r_b, EW, BLR);
    hipLaunchKernelGGL(k_node_enc, dim3(3000), b256, 0, stream, x, node_w, H0, H0F, CNT);
    hipLaunchKernelGGL(k_bucket, dim3(47), b256, 0, stream, ei, CNT, EB);

    for (int i = 0; i < 2; ++i) {
        hipLaunchKernelGGL(k_mm16, dim3(94, 4), b256, 0, stream,
                           H0F, WTh + i * 32768, WTl + i * 32768,
                           BLR + i * 256, XLXR, NN, 256);
        hipLaunchKernelGGL(k_gat_fused, dim3(1500), b256, 0, stream,
                           XLXR, ei, eattr, CNT, EB, EW + i * 640, gat_att + i * 128,
                           H0, gat_bias + i * 128, gat_ln_g + i * 128, gat_ln_b + i * 128,
                           (i == 0) ? H0F : TF);
    }

    // initial conv (layer-0 weights): T = f16(h0 post-GAT), no residual
    hipLaunchKernelGGL(k_convmm, dim3(188), b256, 0, stream,
                       TF, ei, eattr, CNT, EB, B2h, B2l, nn_bias,
                       H0, (const float*)nullptr, H, TF,
                       dec_g, dec_b, 0,
                       (const float*)nullptr, (const float*)nullptr, (float*)nullptr);

    for (int i = 0; i < 8; ++i) {
        int fin = (i == 7);
        hipLaunchKernelGGL(k_convmm, dim3(188), b256, 0, stream,
                           TF, ei, eattr, CNT, EB,
                           B2h + (size_t)i * 98304, B2l + (size_t)i * 98304,
                           nn_bias + i * 128, H0, H, H, TF,
                           fin ? dec_g : dec_g + (i + 1) * 128,
                           fin ? dec_b : dec_b + (i + 1) * 128,
                           fin, out_w, out_b, out);
    }
}